// Round 9
// baseline (281.960 us; speedup 1.0000x reference)
//
#include <hip/hip_runtime.h>
#include <type_traits>
#include <utility>

typedef unsigned short u16;
typedef unsigned int u32;
typedef short short8 __attribute__((ext_vector_type(8)));
typedef __bf16 bf16x8 __attribute__((ext_vector_type(8)));
typedef float floatx4 __attribute__((ext_vector_type(4)));

// ---- MFMA wrapper robust to either builtin signature (short8 vs v8bf16) ----
template <typename V, typename = void> struct MfmaTakes : std::false_type {};
template <typename V>
struct MfmaTakes<V, std::void_t<decltype(__builtin_amdgcn_mfma_f32_16x16x32_bf16(
    std::declval<V>(), std::declval<V>(), std::declval<floatx4>(), 0, 0, 0))>>
    : std::true_type {};

template <typename V>
__device__ __forceinline__ floatx4 mfma_impl(V a, V b, floatx4 c, std::true_type) {
  return __builtin_amdgcn_mfma_f32_16x16x32_bf16(a, b, c, 0, 0, 0);
}
template <typename V>
__device__ __forceinline__ floatx4 mfma_impl(V a, V b, floatx4 c, std::false_type) {
  return __builtin_amdgcn_mfma_f32_16x16x32_bf16(
      __builtin_bit_cast(bf16x8, a), __builtin_bit_cast(bf16x8, b), c, 0, 0, 0);
}
__device__ __forceinline__ floatx4 MFMA16(short8 a, short8 b, floatx4 c) {
  return mfma_impl<short8>(a, b, c, MfmaTakes<short8>{});
}

__device__ __forceinline__ u16 f2bf(float f) {
  union { float f; unsigned u; } x; x.f = f;
  unsigned r = (x.u + 0x7fffu + ((x.u >> 16) & 1u)) >> 16;
  return (u16)r;
}
__device__ __forceinline__ float bf2f(u16 v) {
  union { unsigned u; float f; } x; x.u = ((unsigned)v) << 16; return x.f;
}
__device__ __forceinline__ u32 packbf(float lo, float hi) {  // truncation pack (P)
  return (__float_as_uint(hi) & 0xffff0000u) | (__float_as_uint(lo) >> 16);
}
__device__ __forceinline__ u32 pack2bf(float lo, float hi) {  // round-nearest pack
  return ((u32)f2bf(hi) << 16) | (u32)f2bf(lo);
}

// ---- async global->LDS staging (16B/lane), fallback to vector copy ----
#if defined(__has_builtin)
#if __has_builtin(__builtin_amdgcn_global_load_lds)
#define HAS_GLLDS 1
#endif
#endif
__device__ __forceinline__ void stage16(const u16* g, u16* lbase, int lane) {
#ifdef HAS_GLLDS
  __builtin_amdgcn_global_load_lds(
      (__attribute__((address_space(1))) void*)(g),
      (__attribute__((address_space(3))) void*)(lbase), 16, 0, 0);
#else
  *(uint4*)(lbase + lane * 8) = *(const uint4*)g;
#endif
}

// ---------------- prep: x->bf16, concat W->bf16, out_w->bf16, lambda weights
__global__ __launch_bounds__(256) void prep_kernel(
    const float* __restrict__ x, const float* __restrict__ qw,
    const float* __restrict__ kw, const float* __restrict__ vw,
    const float* __restrict__ outw, const float* __restrict__ lam,
    u16* __restrict__ xb, u16* __restrict__ wcat, u16* __restrict__ outwb,
    float* __restrict__ lwbuf) {
  size_t gid = (size_t)blockIdx.x * 256 + threadIdx.x;
  if (gid == 0) {
    float s0 = 1.f / (1.f + expf(-lam[0]));
    float s1 = 1.f / (1.f + expf(-lam[1]));
    float s2 = 1.f / (1.f + expf(-lam[2]));
    float mean = (s0 + s1 + s2) * (1.f / 3.f);
    float d0 = s0 - mean, d1 = s1 - mean, d2 = s2 - mean;
    float var = (d0 * d0 + d1 * d1 + d2 * d2) * (1.f / 3.f);
    float r = rsqrtf(var + 1e-5f);
    lwbuf[0] = d0 * r; lwbuf[1] = d1 * r; lwbuf[2] = d2 * r;
  }
  if (gid < 524288) {
    float4 v = ((const float4*)x)[gid];
    ushort4 o; o.x = f2bf(v.x); o.y = f2bf(v.y); o.z = f2bf(v.z); o.w = f2bf(v.w);
    ((ushort4*)xb)[gid] = o;
    return;
  }
  size_t g2 = gid - 524288;
  if (g2 < 1572864) {  // wcat rows: [layer][q(1024)|k(512)|v(512)] x 1024 cols
    int col4 = (int)(g2 & 255);
    int n = (int)(g2 >> 8);
    int layer = n >> 11, r = n & 2047;
    const float* srcrow;
    if (r < 1024) srcrow = qw + ((size_t)(layer * 1024 + r) << 10);
    else if (r < 1536) srcrow = kw + ((size_t)(layer * 512 + (r - 1024)) << 10);
    else srcrow = vw + ((size_t)(layer * 512 + (r - 1536)) << 10);
    float4 v = ((const float4*)srcrow)[col4];
    ushort4 o; o.x = f2bf(v.x); o.y = f2bf(v.y); o.z = f2bf(v.z); o.w = f2bf(v.w);
    ((ushort4*)wcat)[g2] = o;
    return;
  }
  size_t g3 = g2 - 1572864;
  if (g3 < 262144) {
    float4 v = ((const float4*)outw)[g3];
    ushort4 o; o.x = f2bf(v.x); o.y = f2bf(v.y); o.z = f2bf(v.z); o.w = f2bf(v.w);
    ((ushort4*)outwb)[g3] = o;
  }
}

// ---------------- fused QKV GEMM: 128x128 tile + in-epilogue RoPE/scatter.
// Epilogue routes fragments through a per-wave LDS transpose tile so every
// global store is a coalesced dwordx4 (1KB/wave-instr for Q/K, 128B lines for V).
__global__ __launch_bounds__(256) void gemm_qkv(
    const u16* __restrict__ A, const u16* __restrict__ Bw,
    const float* __restrict__ cosb, const float* __restrict__ sinb,
    u16* __restrict__ qr, u16* __restrict__ kr, u16* __restrict__ vt) {
  __shared__ u16 As[128][64];
  __shared__ u16 Bs[128][64];
  const unsigned flat = blockIdx.x;
  const int bm = (flat >> 3) & 15;
  const int bn = ((flat >> 7) << 3) + (flat & 7);  // same bn -> same XCD
  const int tid = threadIdx.x;
  const int wave = tid >> 6, lane = tid & 63;
  const int quad = lane >> 4, l16 = lane & 15;
  const int wm = wave & 1, wn = wave >> 1;
  const int srow = lane >> 3, skc = (lane & 7) * 8;
  floatx4 acc[4][4];
#pragma unroll
  for (int i = 0; i < 4; i++)
#pragma unroll
    for (int j = 0; j < 4; j++) { acc[i][j][0] = 0.f; acc[i][j][1] = 0.f; acc[i][j][2] = 0.f; acc[i][j][3] = 0.f; }
  const u16* Abase = A + (size_t)(bm * 128) * 1024;
  const u16* Bbase = Bw + (size_t)(bn * 128) * 1024;
  for (int k0 = 0; k0 < 1024; k0 += 64) {
    __syncthreads();
#pragma unroll
    for (int i = 0; i < 4; i++) {
      int ch = wave * 4 + i;
      stage16(Abase + (size_t)(ch * 8 + srow) * 1024 + k0 + skc, &As[ch * 8][0], lane);
      stage16(Bbase + (size_t)(ch * 8 + srow) * 1024 + k0 + skc, &Bs[ch * 8][0], lane);
    }
    __syncthreads();
#pragma unroll
    for (int kf = 0; kf < 2; kf++) {
      short8 af[4], bf[4];
#pragma unroll
      for (int mi = 0; mi < 4; mi++)
        af[mi] = *(const short8*)(&As[wm * 64 + mi * 16 + l16][kf * 32 + quad * 8]);
#pragma unroll
      for (int ni = 0; ni < 4; ni++)
        bf[ni] = *(const short8*)(&Bs[wn * 64 + ni * 16 + l16][kf * 32 + quad * 8]);
#pragma unroll
      for (int mi = 0; mi < 4; mi++)
#pragma unroll
        for (int ni = 0; ni < 4; ni++)
          acc[mi][ni] = MFMA16(af[mi], bf[ni], acc[mi][ni]);
    }
  }
  // ---- fused epilogue: per-wave LDS transpose tile (16 rows x 66, padded) ----
  __syncthreads();                       // all MFMA LDS reads done; reuse As
  u16* Tw = (&As[0][0]) + (unsigned)wave * 1056;  // 16*66 u16 per wave
  const int f0 = bn * 128 + wn * 64;     // wave's feature base (uniform type/head)
  const int lay = f0 >> 11;
  const int r0 = f0 & 2047;
  const int mrow0 = bm * 128 + wm * 64;
  const int jrd = lane & 7, trd = lane >> 3;  // read-back coords
  if (r0 < 1536) {                       // ---- Q or K: RoPE then coalesced store
    const bool isQ = (r0 < 1024);
    const int h = isQ ? (r0 >> 6) : ((r0 - 1024) >> 6);
    const float qscale = isQ ? 0.125f : 1.f;
    const int posoff = isQ ? 0 : lay * 1024;
#pragma unroll
    for (int mi = 0; mi < 4; mi++) {
#pragma unroll
      for (int rr = 0; rr < 4; rr++) {
        int m = mrow0 + mi * 16 + quad * 4 + rr;
        int t = m & 1023;
        int pos = posoff + t;
        const float* cp = cosb + (size_t)pos * 32;
        const float* sp = sinb + (size_t)pos * 32;
        float c0 = cp[l16], s0 = sp[l16];
        float c1 = cp[16 + l16], s1 = sp[16 + l16];
        float x10 = acc[mi][0][rr], x20 = acc[mi][2][rr];
        float x11 = acc[mi][1][rr], x21 = acc[mi][3][rr];
        u16* trow = Tw + (quad * 4 + rr) * 66;
        trow[l16]      = f2bf((x10 * c0 - x20 * s0) * qscale);
        trow[16 + l16] = f2bf((x11 * c1 - x21 * s1) * qscale);
        trow[32 + l16] = f2bf((x20 * c0 + x10 * s0) * qscale);
        trow[48 + l16] = f2bf((x21 * c1 + x11 * s1) * qscale);
      }
      // read back 2 token-rows/lane-group, store 1KB-contiguous dwordx4
#pragma unroll
      for (int half = 0; half < 2; half++) {
        int tloc = trd + half * 8;
        uint4 val = *(const uint4*)(Tw + tloc * 66 + jrd * 8);
        int m = mrow0 + mi * 16 + tloc;
        int b = m >> 10, t = m & 1023;
        u16* dst;
        if (isQ) dst = qr + ((((size_t)lay * 2 + b) * 16 + h) * 1024 + t) * 64;
        else     dst = kr + (((size_t)(b * 8 + h)) * 3072 + lay * 1024 + t) * 64;
        *(uint4*)(dst + jrd * 8) = val;
      }
    }
  } else {                               // ---- V: transpose to [d][pos]
    const int hv = (r0 - 1536) >> 6;
    const int b = mrow0 >> 10;           // uniform within the wave's 64 tokens
    const int posb = lay * 1024 + (mrow0 & 1023);
#pragma unroll
    for (int ni = 0; ni < 4; ni++) {     // d-chunk of 16
#pragma unroll
      for (int mi = 0; mi < 4; mi++) {
        u16* trow = Tw + l16 * 66 + mi * 16 + quad * 4;
        trow[0] = f2bf(acc[mi][ni][0]);
        trow[1] = f2bf(acc[mi][ni][1]);
        trow[2] = f2bf(acc[mi][ni][2]);
        trow[3] = f2bf(acc[mi][ni][3]);
      }
#pragma unroll
      for (int half = 0; half < 2; half++) {
        int dloc = trd + half * 8;
        uint4 val = *(const uint4*)(Tw + dloc * 66 + jrd * 8);
        u16* dst = vt + ((size_t)(b * 8 + hv) * 64 + ni * 16 + dloc) * 3072 + posb + jrd * 8;
        *(uint4*)dst = val;
      }
    }
  }
}

// ---------------- small GEMM (64x64 tile) for the out-projection
__global__ __launch_bounds__(256) void gemm_bt(
    const u16* __restrict__ A, const u16* __restrict__ Bw,
    float* __restrict__ C, int N, int K) {
  __shared__ u16 As[64][72];
  __shared__ u16 Bs[64][72];
  const int bm = blockIdx.x, bn = blockIdx.y;
  const int tid = threadIdx.x;
  const int wave = tid >> 6, lane = tid & 63;
  const int quad = lane >> 4, l16 = lane & 15;
  const int lr = tid >> 2, lc = (tid & 3) << 4;
  floatx4 acc[4];
#pragma unroll
  for (int i = 0; i < 4; i++) { acc[i][0] = 0.f; acc[i][1] = 0.f; acc[i][2] = 0.f; acc[i][3] = 0.f; }
  const u16* Arow = A + (size_t)(bm * 64 + lr) * K;
  const u16* Brow = Bw + (size_t)(bn * 64 + lr) * K;
  for (int k0 = 0; k0 < K; k0 += 64) {
    __syncthreads();
    *(uint4*)(&As[lr][lc])     = *(const uint4*)(Arow + k0 + lc);
    *(uint4*)(&As[lr][lc + 8]) = *(const uint4*)(Arow + k0 + lc + 8);
    *(uint4*)(&Bs[lr][lc])     = *(const uint4*)(Brow + k0 + lc);
    *(uint4*)(&Bs[lr][lc + 8]) = *(const uint4*)(Brow + k0 + lc + 8);
    __syncthreads();
    const int mrow = wave * 16 + l16;
    short8 a0 = *(const short8*)(&As[mrow][quad * 8]);
    short8 a1 = *(const short8*)(&As[mrow][32 + quad * 8]);
#pragma unroll
    for (int ns = 0; ns < 4; ns++) {
      short8 b0 = *(const short8*)(&Bs[ns * 16 + l16][quad * 8]);
      short8 b1 = *(const short8*)(&Bs[ns * 16 + l16][32 + quad * 8]);
      acc[ns] = MFMA16(a0, b0, acc[ns]);
      acc[ns] = MFMA16(a1, b1, acc[ns]);
    }
  }
#pragma unroll
  for (int ns = 0; ns < 4; ns++)
#pragma unroll
    for (int r = 0; r < 4; r++) {
      int row = bm * 64 + wave * 16 + quad * 4 + r;
      int col = bn * 64 + ns * 16 + l16;
      C[(size_t)row * N + col] = acc[ns][r];
    }
}

// ---------------- attention v6: K staged in LDS; V read directly from global
// as A-operand fragments (contiguous 16B/lane in vt, no barrier dependency,
// prefetched one tile ahead). LDS ops/tile-block 64 -> 44 on the saturated pipe.
__global__ __launch_bounds__(256) void attn_v6(
    const u16* __restrict__ qr, const u16* __restrict__ kr,
    const u16* __restrict__ vt, u16* __restrict__ obS,
    float* __restrict__ lbufp) {
  __shared__ u16 Kt[32][72];      // [key(32)][d]  4608 B
  __shared__ u16 Pw[4][16][40];   // per-wave P / epilogue scratch  5120 B
  const unsigned flat = blockIdx.x;
  const int bhz = (int)((flat >> 6) * 8 + (flat & 7));  // same (bh,z) -> same XCD
  const int qtile = 7 - (int)((flat >> 3) & 7);         // heavy q-tiles first
  const int z = bhz >> 5;
  const int bh = bhz & 31;
  const int lay = (z == 5) ? 0 : ((z == 0 || z == 4) ? 1 : 2);
  const int n = lay * 32 + qtile * 4 + 4;   // total 32-key tiles for this (lay,qtile)
  int kt0, kt1;
  if (lay == 0) { kt0 = 0; kt1 = n; }
  else if (lay == 1) { int hf = n >> 1; kt0 = (z == 0) ? 0 : hf; kt1 = (z == 0) ? hf : n; }
  else {
    int t1 = n / 3, t2 = (2 * n) / 3;
    kt0 = (z == 1) ? 0 : ((z == 2) ? t1 : t2);
    kt1 = (z == 1) ? t1 : ((z == 2) ? t2 : n);
  }
  const int maskkt = lay * 32 + qtile * 4;
  const int b = bh >> 4, h = bh & 15, hk = h >> 1;
  const int tid = threadIdx.x, wave = tid >> 6, lane = tid & 63;
  const int quad = lane >> 4, l16 = lane & 15;
  const int qeffbase = lay * 1024 + qtile * 128 + wave * 32;
  const u16* qpb = qr + ((((size_t)lay * 2 + b) * 16 + h) * 1024
                         + qtile * 128 + wave * 32 + l16) * 64 + quad * 8;
  short8 qf[2][2];
  qf[0][0] = *(const short8*)(qpb);
  qf[0][1] = *(const short8*)(qpb + 32);
  qf[1][0] = *(const short8*)(qpb + 1024);
  qf[1][1] = *(const short8*)(qpb + 1056);
  const short8 ones = {16256, 16256, 16256, 16256, 16256, 16256, 16256, 16256};
  floatx4 oacc[2][4];
#pragma unroll
  for (int nt = 0; nt < 2; nt++)
#pragma unroll
    for (int dt = 0; dt < 4; dt++) { oacc[nt][dt][0] = 0.f; oacc[nt][dt][1] = 0.f; oacc[nt][dt][2] = 0.f; oacc[nt][dt][3] = 0.f; }
  floatx4 lacc[2];
  lacc[0][0] = 0.f; lacc[0][1] = 0.f; lacc[0][2] = 0.f; lacc[0][3] = 0.f;
  lacc[1] = lacc[0];
  const int ksr = tid >> 3, ksc = (tid & 7) * 8;
  const u16* kp = kr + ((size_t)(b * 8 + hk) * 3072 + kt0 * 32 + ksr) * 64 + ksc;
  const u16* vwb = vt + (size_t)(b * 8 + hk) * 64 * 3072 + (size_t)l16 * 3072 + quad * 8;
  uint4 kA = *(const uint4*)kp;           // prime K staging prefetch
  short8 vf[4], vfN[4];
#pragma unroll
  for (int dt = 0; dt < 4; dt++)          // prime V fragment prefetch (tile kt0)
    vfN[dt] = *(const short8*)(vwb + (size_t)(dt * 16) * 3072 + kt0 * 32);
  for (int kt = kt0; kt < kt1; kt++) {
    kp += 2048;
    __syncthreads();
    *(uint4*)(&Kt[ksr][ksc]) = kA;
    if (kt + 1 < kt1) kA = *(const uint4*)kp;
#pragma unroll
    for (int dt = 0; dt < 4; dt++) vf[dt] = vfN[dt];
    if (kt + 1 < kt1) {
#pragma unroll
      for (int dt = 0; dt < 4; dt++)      // V for next tile: latency off the path
        vfN[dt] = *(const short8*)(vwb + (size_t)(dt * 16) * 3072 + (kt + 1) * 32);
    }
    __syncthreads();
    const bool needmask = (kt >= maskkt);
    uint2 pk[2][2];  // [mt][nt]
#pragma unroll
    for (int mt = 0; mt < 2; mt++) {
      short8 kfa = *(const short8*)(&Kt[mt * 16 + l16][quad * 8]);
      short8 kfb = *(const short8*)(&Kt[mt * 16 + l16][32 + quad * 8]);
      const int keyb = kt * 32 + mt * 16 + quad * 4;
#pragma unroll
      for (int nt = 0; nt < 2; nt++) {
        floatx4 s; s[0] = 0.f; s[1] = 0.f; s[2] = 0.f; s[3] = 0.f;
        s = MFMA16(kfa, qf[nt][0], s);
        s = MFMA16(kfb, qf[nt][1], s);
        float p0 = __expf(s[0]), p1 = __expf(s[1]);
        float p2 = __expf(s[2]), p3 = __expf(s[3]);
        if (needmask) {
          int qpos = qeffbase + nt * 16 + l16;
          if (keyb + 0 > qpos) p0 = 0.f;
          if (keyb + 1 > qpos) p1 = 0.f;
          if (keyb + 2 > qpos) p2 = 0.f;
          if (keyb + 3 > qpos) p3 = 0.f;
        }
        pk[mt][nt].x = packbf(p0, p1);
        pk[mt][nt].y = packbf(p2, p3);
      }
    }
#pragma unroll
    for (int nt = 0; nt < 2; nt++) {
      *(uint2*)(&Pw[wave][l16][quad * 4])      = pk[0][nt];
      *(uint2*)(&Pw[wave][l16][16 + quad * 4]) = pk[1][nt];
      short8 pf = *(const short8*)(&Pw[wave][l16][quad * 8]);
      lacc[nt] = MFMA16(ones, pf, lacc[nt]);
#pragma unroll
      for (int dt = 0; dt < 4; dt++)
        oacc[nt][dt] = MFMA16(vf[dt], pf, oacc[nt][dt]);
    }
  }
  // epilogue: O^T (d,t) -> row-major [t][d] via per-wave Pw scratch; bf16 out
  float* Pf = (float*)(&Pw[wave][0][0]);
  const int tt = lane >> 2, dd = (lane & 3) << 2;
#pragma unroll
  for (int nt = 0; nt < 2; nt++) {
    int t = qtile * 128 + wave * 32 + nt * 16 + l16;
    if (quad == 0)
      lbufp[((size_t)z * 2048 + b * 1024 + t) * 16 + h] = lacc[nt][0];
    int t2 = qtile * 128 + wave * 32 + nt * 16 + tt;
    u16* orow = obS + ((size_t)(z * 2 + b) * 1024 + t2) * 1024 + h * 64 + dd;
#pragma unroll
    for (int dt = 0; dt < 4; dt++) {
      *(floatx4*)(&Pf[l16 * 20 + quad * 4]) = oacc[nt][dt];   // [t][d] tile
      floatx4 val = *(const floatx4*)(&Pf[tt * 20 + dd]);     // wave in-order
      uint2 st; st.x = pack2bf(val[0], val[1]); st.y = pack2bf(val[2], val[3]);
      *(uint2*)(orow + dt * 16) = st;
    }
  }
}

// ---------------- fused: slot-sum (bf16 coalesced rows), /l, rmsnorm chain
__device__ __forceinline__ float block_sum(float v, float* red) {
  v += __shfl_xor(v, 32); v += __shfl_xor(v, 16); v += __shfl_xor(v, 8);
  v += __shfl_xor(v, 4);  v += __shfl_xor(v, 2);  v += __shfl_xor(v, 1);
  __syncthreads();
  if ((threadIdx.x & 63) == 0) red[threadIdx.x >> 6] = v;
  __syncthreads();
  return red[0] + red[1] + red[2] + red[3];
}

__global__ __launch_bounds__(256) void fused_norm(
    const u16* __restrict__ obS, const float* __restrict__ lbufp,
    const float* __restrict__ x, const float* __restrict__ lnw,
    const float* __restrict__ lwbuf, const float* __restrict__ flnw,
    const float* __restrict__ alphap, u16* __restrict__ y) {
  __shared__ float red[4];
  const int row = blockIdx.x, tid = threadIdx.x;  // row = b*1024+t
  float a[4] = {0.f, 0.f, 0.f, 0.f};
  const int nsl[3] = {1, 2, 3};
  const int sl[3][3] = {{5, 0, 0}, {0, 4, 0}, {1, 2, 3}};
#pragma unroll
  for (int l = 0; l < 3; l++) {
    float o0 = 0.f, o1 = 0.f, o2 = 0.f, o3 = 0.f, ls = 0.f;
#pragma unroll
    for (int si = 0; si < 3; si++) {
      if (si >= nsl[l]) break;
      int z = sl[l][si];
      uint2 v = ((const uint2*)(obS + ((size_t)z * 2048 + row) * 1024))[tid];
      o0 += bf2f((u16)(v.x & 0xffff)); o1 += bf2f((u16)(v.x >> 16));
      o2 += bf2f((u16)(v.y & 0xffff)); o3 += bf2f((u16)(v.y >> 16));
      ls += lbufp[((size_t)z * 2048 + row) * 16 + (tid >> 4)];
    }
    float linv = 1.f / ls;
    float v0 = o0 * linv, v1 = o1 * linv, v2 = o2 * linv, v3 = o3 * linv;
    float ss = v0 * v0 + v1 * v1 + v2 * v2 + v3 * v3;
    ss = block_sum(ss, red);
    float rstd = rsqrtf(ss * (1.f / 1024.f) + 1e-5f);
    float lw = lwbuf[l];
    float4 w = ((const float4*)(lnw + (size_t)l * 1024))[tid];
    a[0] += v0 * rstd * w.x * lw;
    a[1] += v1 * rstd * w.y * lw;
    a[2] += v2 * rstd * w.z * lw;
    a[3] += v3 * rstd * w.w * lw;
  }
  const float aa = alphap[0];
  float4 xv = ((const float4*)(x + (size_t)row * 1024))[tid];
  float v0 = a[0] + aa * xv.x, v1 = a[1] + aa * xv.y;
  float v2 = a[2] + aa * xv.z, v3 = a[3] + aa * xv.w;
  float ss = v0 * v0 + v1 * v1 + v2 * v2 + v3 * v3;
  ss = block_sum(ss, red);
  float rstd = rsqrtf(ss * (1.f / 1024.f) + 1e-5f);
  float4 fw = ((const float4*)flnw)[tid];
  ushort4 o;
  o.x = f2bf(v0 * rstd * fw.x); o.y = f2bf(v1 * rstd * fw.y);
  o.z = f2bf(v2 * rstd * fw.z); o.w = f2bf(v3 * rstd * fw.w);
  ((ushort4*)(y + (size_t)row * 1024))[tid] = o;
}

extern "C" void kernel_launch(void* const* d_in, const int* in_sizes, int n_in,
                              void* d_out, int out_size, void* d_ws, size_t ws_size,
                              hipStream_t stream) {
  const float* x     = (const float*)d_in[0];
  const float* cosb  = (const float*)d_in[1];
  const float* sinb  = (const float*)d_in[2];
  const float* qw    = (const float*)d_in[3];
  const float* kw    = (const float*)d_in[4];
  const float* vw    = (const float*)d_in[5];
  const float* lnw   = (const float*)d_in[6];
  const float* lam   = (const float*)d_in[7];
  const float* outw  = (const float*)d_in[8];
  const float* flnw  = (const float*)d_in[9];
  const float* alphap= (const float*)d_in[10];
  float* out = (float*)d_out;
  char* ws = (char*)d_ws;
  // workspace (~57.4 MB). Region [0,24M) is time-shared:
  //   phase 1 (prep/gemm_qkv): xb [0,4M) + wcat [4M,16M)
  //   phase 2 (attn/fused_norm): obS [0,24M)  bf16 [z][b][t][h*64+d]
  u16*   xb    = (u16*)  (ws + 0);          //  4 MB
  u16*   wcat  = (u16*)  (ws + 4194304);    // 12 MB
  u16*   obS   = (u16*)  (ws + 0);          // 24 MB (phase 2)
  u16*   outwb = (u16*)  (ws + 25165824);   //  2 MB
  float* lwbuf = (float*)(ws + 27262976);   //  1 KB
  u16*   qr    = (u16*)  (ws + 27264000);   // 12 MB  [3][2][16][1024][64]
  u16*   kr    = (u16*)  (ws + 39846912);   //  6 MB  [2][8][3072][64]
  u16*   vt    = (u16*)  (ws + 46138368);   //  6 MB  [2][8][64][3072]
  float* lbufp = (float*)(ws + 52429824);   // 768 KB [6][2048][16]
  u16*   yb    = (u16*)  (ws + 53216256);   //  4 MB

  prep_kernel<<<9216, 256, 0, stream>>>(x, qw, kw, vw, outw, lam, xb, wcat, outwb, lwbuf);
  gemm_qkv<<<768, 256, 0, stream>>>(xb, wcat, cosb, sinb, qr, kr, vt);
  attn_v6<<<1536, 256, 0, stream>>>(qr, kr, vt, obS, lbufp);
  fused_norm<<<2048, 256, 0, stream>>>(obS, lbufp, x, lnw, lwbuf, flnw, alphap, yb);
  gemm_bt<<<dim3(32, 16), 256, 0, stream>>>(yb, outwb, out, 1024, 1024);
}

// Round 10
// 256.111 us; speedup vs baseline: 1.1009x; 1.1009x over previous
//
#include <hip/hip_runtime.h>
#include <type_traits>
#include <utility>

typedef unsigned short u16;
typedef unsigned int u32;
typedef short short8 __attribute__((ext_vector_type(8)));
typedef __bf16 bf16x8 __attribute__((ext_vector_type(8)));
typedef float floatx4 __attribute__((ext_vector_type(4)));

// ---- MFMA wrapper robust to either builtin signature (short8 vs v8bf16) ----
template <typename V, typename = void> struct MfmaTakes : std::false_type {};
template <typename V>
struct MfmaTakes<V, std::void_t<decltype(__builtin_amdgcn_mfma_f32_16x16x32_bf16(
    std::declval<V>(), std::declval<V>(), std::declval<floatx4>(), 0, 0, 0))>>
    : std::true_type {};

template <typename V>
__device__ __forceinline__ floatx4 mfma_impl(V a, V b, floatx4 c, std::true_type) {
  return __builtin_amdgcn_mfma_f32_16x16x32_bf16(a, b, c, 0, 0, 0);
}
template <typename V>
__device__ __forceinline__ floatx4 mfma_impl(V a, V b, floatx4 c, std::false_type) {
  return __builtin_amdgcn_mfma_f32_16x16x32_bf16(
      __builtin_bit_cast(bf16x8, a), __builtin_bit_cast(bf16x8, b), c, 0, 0, 0);
}
__device__ __forceinline__ floatx4 MFMA16(short8 a, short8 b, floatx4 c) {
  return mfma_impl<short8>(a, b, c, MfmaTakes<short8>{});
}

__device__ __forceinline__ u16 f2bf(float f) {
  union { float f; unsigned u; } x; x.f = f;
  unsigned r = (x.u + 0x7fffu + ((x.u >> 16) & 1u)) >> 16;
  return (u16)r;
}
__device__ __forceinline__ float bf2f(u16 v) {
  union { unsigned u; float f; } x; x.u = ((unsigned)v) << 16; return x.f;
}
__device__ __forceinline__ u32 packbf(float lo, float hi) {  // truncation pack (P)
  return (__float_as_uint(hi) & 0xffff0000u) | (__float_as_uint(lo) >> 16);
}
__device__ __forceinline__ u32 pack2bf(float lo, float hi) {  // round-nearest pack
  return ((u32)f2bf(hi) << 16) | (u32)f2bf(lo);
}

// ---- async global->LDS staging (16B/lane), fallback to vector copy ----
#if defined(__has_builtin)
#if __has_builtin(__builtin_amdgcn_global_load_lds)
#define HAS_GLLDS 1
#endif
#endif
__device__ __forceinline__ void stage16(const u16* g, u16* lbase, int lane) {
#ifdef HAS_GLLDS
  __builtin_amdgcn_global_load_lds(
      (__attribute__((address_space(1))) void*)(g),
      (__attribute__((address_space(3))) void*)(lbase), 16, 0, 0);
#else
  *(uint4*)(lbase + lane * 8) = *(const uint4*)g;
#endif
}

// ---------------- prep: x->bf16, concat W->bf16, out_w->bf16, lambda weights
__global__ __launch_bounds__(256) void prep_kernel(
    const float* __restrict__ x, const float* __restrict__ qw,
    const float* __restrict__ kw, const float* __restrict__ vw,
    const float* __restrict__ outw, const float* __restrict__ lam,
    u16* __restrict__ xb, u16* __restrict__ wcat, u16* __restrict__ outwb,
    float* __restrict__ lwbuf) {
  size_t gid = (size_t)blockIdx.x * 256 + threadIdx.x;
  if (gid == 0) {
    float s0 = 1.f / (1.f + expf(-lam[0]));
    float s1 = 1.f / (1.f + expf(-lam[1]));
    float s2 = 1.f / (1.f + expf(-lam[2]));
    float mean = (s0 + s1 + s2) * (1.f / 3.f);
    float d0 = s0 - mean, d1 = s1 - mean, d2 = s2 - mean;
    float var = (d0 * d0 + d1 * d1 + d2 * d2) * (1.f / 3.f);
    float r = rsqrtf(var + 1e-5f);
    lwbuf[0] = d0 * r; lwbuf[1] = d1 * r; lwbuf[2] = d2 * r;
  }
  if (gid < 524288) {
    float4 v = ((const float4*)x)[gid];
    ushort4 o; o.x = f2bf(v.x); o.y = f2bf(v.y); o.z = f2bf(v.z); o.w = f2bf(v.w);
    ((ushort4*)xb)[gid] = o;
    return;
  }
  size_t g2 = gid - 524288;
  if (g2 < 1572864) {  // wcat rows: [layer][q(1024)|k(512)|v(512)] x 1024 cols
    int col4 = (int)(g2 & 255);
    int n = (int)(g2 >> 8);
    int layer = n >> 11, r = n & 2047;
    const float* srcrow;
    if (r < 1024) srcrow = qw + ((size_t)(layer * 1024 + r) << 10);
    else if (r < 1536) srcrow = kw + ((size_t)(layer * 512 + (r - 1024)) << 10);
    else srcrow = vw + ((size_t)(layer * 512 + (r - 1536)) << 10);
    float4 v = ((const float4*)srcrow)[col4];
    ushort4 o; o.x = f2bf(v.x); o.y = f2bf(v.y); o.z = f2bf(v.z); o.w = f2bf(v.w);
    ((ushort4*)wcat)[g2] = o;
    return;
  }
  size_t g3 = g2 - 1572864;
  if (g3 < 262144) {
    float4 v = ((const float4*)outw)[g3];
    ushort4 o; o.x = f2bf(v.x); o.y = f2bf(v.y); o.z = f2bf(v.z); o.w = f2bf(v.w);
    ((ushort4*)outwb)[g3] = o;
  }
}

// ---------------- fused QKV GEMM: 128x128 tile + in-epilogue RoPE/scatter.
// Epilogue routes fragments through a per-wave LDS transpose tile so every
// global store is a coalesced dwordx4.
__global__ __launch_bounds__(256) void gemm_qkv(
    const u16* __restrict__ A, const u16* __restrict__ Bw,
    const float* __restrict__ cosb, const float* __restrict__ sinb,
    u16* __restrict__ qr, u16* __restrict__ kr, u16* __restrict__ vt) {
  __shared__ u16 As[128][64];
  __shared__ u16 Bs[128][64];
  const unsigned flat = blockIdx.x;
  const int bm = (flat >> 3) & 15;
  const int bn = ((flat >> 7) << 3) + (flat & 7);  // same bn -> same XCD
  const int tid = threadIdx.x;
  const int wave = tid >> 6, lane = tid & 63;
  const int quad = lane >> 4, l16 = lane & 15;
  const int wm = wave & 1, wn = wave >> 1;
  const int srow = lane >> 3, skc = (lane & 7) * 8;
  floatx4 acc[4][4];
#pragma unroll
  for (int i = 0; i < 4; i++)
#pragma unroll
    for (int j = 0; j < 4; j++) { acc[i][j][0] = 0.f; acc[i][j][1] = 0.f; acc[i][j][2] = 0.f; acc[i][j][3] = 0.f; }
  const u16* Abase = A + (size_t)(bm * 128) * 1024;
  const u16* Bbase = Bw + (size_t)(bn * 128) * 1024;
  for (int k0 = 0; k0 < 1024; k0 += 64) {
    __syncthreads();
#pragma unroll
    for (int i = 0; i < 4; i++) {
      int ch = wave * 4 + i;
      stage16(Abase + (size_t)(ch * 8 + srow) * 1024 + k0 + skc, &As[ch * 8][0], lane);
      stage16(Bbase + (size_t)(ch * 8 + srow) * 1024 + k0 + skc, &Bs[ch * 8][0], lane);
    }
    __syncthreads();
#pragma unroll
    for (int kf = 0; kf < 2; kf++) {
      short8 af[4], bf[4];
#pragma unroll
      for (int mi = 0; mi < 4; mi++)
        af[mi] = *(const short8*)(&As[wm * 64 + mi * 16 + l16][kf * 32 + quad * 8]);
#pragma unroll
      for (int ni = 0; ni < 4; ni++)
        bf[ni] = *(const short8*)(&Bs[wn * 64 + ni * 16 + l16][kf * 32 + quad * 8]);
#pragma unroll
      for (int mi = 0; mi < 4; mi++)
#pragma unroll
        for (int ni = 0; ni < 4; ni++)
          acc[mi][ni] = MFMA16(af[mi], bf[ni], acc[mi][ni]);
    }
  }
  // ---- fused epilogue: per-wave LDS transpose tile (16 rows x 66, padded) ----
  __syncthreads();                       // all MFMA LDS reads done; reuse As
  u16* Tw = (&As[0][0]) + (unsigned)wave * 1056;  // 16*66 u16 per wave
  const int f0 = bn * 128 + wn * 64;     // wave's feature base (uniform type/head)
  const int lay = f0 >> 11;
  const int r0 = f0 & 2047;
  const int mrow0 = bm * 128 + wm * 64;
  const int jrd = lane & 7, trd = lane >> 3;  // read-back coords
  if (r0 < 1536) {                       // ---- Q or K: RoPE then coalesced store
    const bool isQ = (r0 < 1024);
    const int h = isQ ? (r0 >> 6) : ((r0 - 1024) >> 6);
    const float qscale = isQ ? 0.125f : 1.f;
    const int posoff = isQ ? 0 : lay * 1024;
#pragma unroll
    for (int mi = 0; mi < 4; mi++) {
#pragma unroll
      for (int rr = 0; rr < 4; rr++) {
        int m = mrow0 + mi * 16 + quad * 4 + rr;
        int t = m & 1023;
        int pos = posoff + t;
        const float* cp = cosb + (size_t)pos * 32;
        const float* sp = sinb + (size_t)pos * 32;
        float c0 = cp[l16], s0 = sp[l16];
        float c1 = cp[16 + l16], s1 = sp[16 + l16];
        float x10 = acc[mi][0][rr], x20 = acc[mi][2][rr];
        float x11 = acc[mi][1][rr], x21 = acc[mi][3][rr];
        u16* trow = Tw + (quad * 4 + rr) * 66;
        trow[l16]      = f2bf((x10 * c0 - x20 * s0) * qscale);
        trow[16 + l16] = f2bf((x11 * c1 - x21 * s1) * qscale);
        trow[32 + l16] = f2bf((x20 * c0 + x10 * s0) * qscale);
        trow[48 + l16] = f2bf((x21 * c1 + x11 * s1) * qscale);
      }
#pragma unroll
      for (int half = 0; half < 2; half++) {
        int tloc = trd + half * 8;
        uint4 val = *(const uint4*)(Tw + tloc * 66 + jrd * 8);
        int m = mrow0 + mi * 16 + tloc;
        int b = m >> 10, t = m & 1023;
        u16* dst;
        if (isQ) dst = qr + ((((size_t)lay * 2 + b) * 16 + h) * 1024 + t) * 64;
        else     dst = kr + (((size_t)(b * 8 + h)) * 3072 + lay * 1024 + t) * 64;
        *(uint4*)(dst + jrd * 8) = val;
      }
    }
  } else {                               // ---- V: transpose to [d][pos]
    const int hv = (r0 - 1536) >> 6;
    const int b = mrow0 >> 10;
    const int posb = lay * 1024 + (mrow0 & 1023);
#pragma unroll
    for (int ni = 0; ni < 4; ni++) {     // d-chunk of 16
#pragma unroll
      for (int mi = 0; mi < 4; mi++) {
        u16* trow = Tw + l16 * 66 + mi * 16 + quad * 4;
        trow[0] = f2bf(acc[mi][ni][0]);
        trow[1] = f2bf(acc[mi][ni][1]);
        trow[2] = f2bf(acc[mi][ni][2]);
        trow[3] = f2bf(acc[mi][ni][3]);
      }
#pragma unroll
      for (int half = 0; half < 2; half++) {
        int dloc = trd + half * 8;
        uint4 val = *(const uint4*)(Tw + dloc * 66 + jrd * 8);
        u16* dst = vt + ((size_t)(b * 8 + hv) * 64 + ni * 16 + dloc) * 3072 + posb + jrd * 8;
        *(uint4*)dst = val;
      }
    }
  }
}

// ---------------- small GEMM (64x64 tile) for the out-projection
__global__ __launch_bounds__(256) void gemm_bt(
    const u16* __restrict__ A, const u16* __restrict__ Bw,
    float* __restrict__ C, int N, int K) {
  __shared__ u16 As[64][72];
  __shared__ u16 Bs[64][72];
  const int bm = blockIdx.x, bn = blockIdx.y;
  const int tid = threadIdx.x;
  const int wave = tid >> 6, lane = tid & 63;
  const int quad = lane >> 4, l16 = lane & 15;
  const int lr = tid >> 2, lc = (tid & 3) << 4;
  floatx4 acc[4];
#pragma unroll
  for (int i = 0; i < 4; i++) { acc[i][0] = 0.f; acc[i][1] = 0.f; acc[i][2] = 0.f; acc[i][3] = 0.f; }
  const u16* Arow = A + (size_t)(bm * 64 + lr) * K;
  const u16* Brow = Bw + (size_t)(bn * 64 + lr) * K;
  for (int k0 = 0; k0 < K; k0 += 64) {
    __syncthreads();
    *(uint4*)(&As[lr][lc])     = *(const uint4*)(Arow + k0 + lc);
    *(uint4*)(&As[lr][lc + 8]) = *(const uint4*)(Arow + k0 + lc + 8);
    *(uint4*)(&Bs[lr][lc])     = *(const uint4*)(Brow + k0 + lc);
    *(uint4*)(&Bs[lr][lc + 8]) = *(const uint4*)(Brow + k0 + lc + 8);
    __syncthreads();
    const int mrow = wave * 16 + l16;
    short8 a0 = *(const short8*)(&As[mrow][quad * 8]);
    short8 a1 = *(const short8*)(&As[mrow][32 + quad * 8]);
#pragma unroll
    for (int ns = 0; ns < 4; ns++) {
      short8 b0 = *(const short8*)(&Bs[ns * 16 + l16][quad * 8]);
      short8 b1 = *(const short8*)(&Bs[ns * 16 + l16][32 + quad * 8]);
      acc[ns] = MFMA16(a0, b0, acc[ns]);
      acc[ns] = MFMA16(a1, b1, acc[ns]);
    }
  }
#pragma unroll
  for (int ns = 0; ns < 4; ns++)
#pragma unroll
    for (int r = 0; r < 4; r++) {
      int row = bm * 64 + wave * 16 + quad * 4 + r;
      int col = bn * 64 + ns * 16 + l16;
      C[(size_t)row * N + col] = acc[ns][r];
    }
}

// ---------------- attention v7: NO P round-trip.
// K rows are PERMUTED in LDS (slot(a) = 4*(a>>3)+(a&3)+16*((a>>2)&1)) so the
// mt0/mt1 S^T MFMA pair leaves lane (quad,l16) holding P[keys 8q..8q+7][query
// l16] — exactly the PV B-operand fragment. exp->pack->MFMA stays in registers.
// 64 queries/wave (nt=4) halves K/V-read intensity; Kt split into two
// stride-40 halves (2-way banks, vs 8-way at stride-72). LDS 10.2 KB.
__global__ __launch_bounds__(256) void attn_v7(
    const u16* __restrict__ qr, const u16* __restrict__ kr,
    const u16* __restrict__ vt, u16* __restrict__ obS,
    float* __restrict__ lbufp) {
  __shared__ u16 Kt2[2][32][40];  // [half d][key slot][d%32]  5120 B
  __shared__ u16 Vtt[64][40];     // [d][key(32)]              5120 B
  const unsigned flat = blockIdx.x;
  const int bhz = (int)((flat & 7) + ((flat >> 5) << 3));  // same (bh,z) -> same XCD
  const int qtile = 3 - (int)((flat >> 3) & 3);            // heavy q-tiles first
  const int z = bhz >> 5;
  const int bh = bhz & 31;
  const int lay = (z == 5) ? 0 : ((z == 0 || z == 4) ? 1 : 2);
  const int n = lay * 32 + qtile * 8 + 8;   // total 32-key tiles for (lay,qtile)
  int kt0, kt1;
  if (lay == 0) { kt0 = 0; kt1 = n; }
  else if (lay == 1) { int hf = n >> 1; kt0 = (z == 0) ? 0 : hf; kt1 = (z == 0) ? hf : n; }
  else {
    int t1 = n / 3, t2 = (2 * n) / 3;
    kt0 = (z == 1) ? 0 : ((z == 2) ? t1 : t2);
    kt1 = (z == 1) ? t1 : ((z == 2) ? t2 : n);
  }
  const int maskkt = lay * 32 + qtile * 8;
  const int b = bh >> 4, h = bh & 15, hk = h >> 1;
  const int tid = threadIdx.x, wave = tid >> 6, lane = tid & 63;
  const int quad = lane >> 4, l16 = lane & 15;
  const int qeffbase = lay * 1024 + qtile * 256 + wave * 64;
  const u16* qpb = qr + ((((size_t)lay * 2 + b) * 16 + h) * 1024
                         + qtile * 256 + wave * 64 + l16) * 64 + quad * 8;
  short8 qf[4][2];
#pragma unroll
  for (int nt = 0; nt < 4; nt++) {
    qf[nt][0] = *(const short8*)(qpb + nt * 1024);
    qf[nt][1] = *(const short8*)(qpb + nt * 1024 + 32);
  }
  const short8 ones = {16256, 16256, 16256, 16256, 16256, 16256, 16256, 16256};
  floatx4 oacc[4][4];
#pragma unroll
  for (int nt = 0; nt < 4; nt++)
#pragma unroll
    for (int dt = 0; dt < 4; dt++) { oacc[nt][dt][0] = 0.f; oacc[nt][dt][1] = 0.f; oacc[nt][dt][2] = 0.f; oacc[nt][dt][3] = 0.f; }
  floatx4 lacc[4];
#pragma unroll
  for (int nt = 0; nt < 4; nt++) { lacc[nt][0] = 0.f; lacc[nt][1] = 0.f; lacc[nt][2] = 0.f; lacc[nt][3] = 0.f; }
  // staging: K rows permuted to slots; V natural
  const int ksr = tid >> 3, ksc = (tid & 7) * 8;
  const int ksl = ((ksr >> 3) << 2) + (ksr & 3) + (((ksr >> 2) & 1) << 4);
  u16* kdst = (ksc < 32) ? &Kt2[0][ksl][ksc] : &Kt2[1][ksl][ksc - 32];
  const int vdr = tid >> 2, vdc = (tid & 3) * 8;
  const u16* kp = kr + ((size_t)(b * 8 + hk) * 3072 + kt0 * 32 + ksr) * 64 + ksc;
  const u16* vp = vt + ((size_t)(b * 8 + hk) * 64 + vdr) * 3072 + kt0 * 32 + vdc;
  uint4 kA = *(const uint4*)kp;   // prime prefetch
  uint4 vA = *(const uint4*)vp;
  for (int kt = kt0; kt < kt1; kt++) {
    kp += 2048; vp += 32;
    __syncthreads();
    *(uint4*)kdst = kA;
    *(uint4*)(&Vtt[vdr][vdc]) = vA;
    if (kt + 1 < kt1) { kA = *(const uint4*)kp; vA = *(const uint4*)vp; }
    __syncthreads();
    const bool needmask = (kt >= maskkt);
    uint2 pk[4][2];  // [nt][mt] -> assembled B-frag (keys 8q+mt*4 .. +3)
#pragma unroll
    for (int mt = 0; mt < 2; mt++) {
      short8 kfa = *(const short8*)(&Kt2[0][mt * 16 + l16][quad * 8]);
      short8 kfb = *(const short8*)(&Kt2[1][mt * 16 + l16][quad * 8]);
      const int keyb = kt * 32 + quad * 8 + mt * 4;   // abs key of reg 0
#pragma unroll
      for (int nt = 0; nt < 4; nt++) {
        floatx4 s; s[0] = 0.f; s[1] = 0.f; s[2] = 0.f; s[3] = 0.f;
        s = MFMA16(kfa, qf[nt][0], s);
        s = MFMA16(kfb, qf[nt][1], s);
        float p0 = __expf(s[0]), p1 = __expf(s[1]);
        float p2 = __expf(s[2]), p3 = __expf(s[3]);
        if (needmask) {
          int qpos = qeffbase + nt * 16 + l16;
          if (keyb + 0 > qpos) p0 = 0.f;
          if (keyb + 1 > qpos) p1 = 0.f;
          if (keyb + 2 > qpos) p2 = 0.f;
          if (keyb + 3 > qpos) p3 = 0.f;
        }
        pk[nt][mt].x = packbf(p0, p1);
        pk[nt][mt].y = packbf(p2, p3);
      }
    }
    short8 vf[4];
#pragma unroll
    for (int dt = 0; dt < 4; dt++)
      vf[dt] = *(const short8*)(&Vtt[dt * 16 + l16][quad * 8]);
#pragma unroll
    for (int nt = 0; nt < 4; nt++) {
      union { uint4 u; short8 s; } pf;
      pf.u.x = pk[nt][0].x; pf.u.y = pk[nt][0].y;
      pf.u.z = pk[nt][1].x; pf.u.w = pk[nt][1].y;
      lacc[nt] = MFMA16(ones, pf.s, lacc[nt]);
#pragma unroll
      for (int dt = 0; dt < 4; dt++)
        oacc[nt][dt] = MFMA16(vf[dt], pf.s, oacc[nt][dt]);
    }
  }
  // epilogue: O^T (d,t) -> row-major [t][d] via per-wave scratch in Kt2; bf16
  __syncthreads();  // all waves done reading Kt2/Vtt
  float* Pf = (float*)(&Kt2[0][0][0]) + (unsigned)wave * 320;  // 1280 B/wave
  const int tt = lane >> 2, dd = (lane & 3) << 2;
#pragma unroll
  for (int nt = 0; nt < 4; nt++) {
    int t = qtile * 256 + wave * 64 + nt * 16 + l16;
    if (quad == 0)
      lbufp[((size_t)z * 2048 + b * 1024 + t) * 16 + h] = lacc[nt][0];
    int t2 = qtile * 256 + wave * 64 + nt * 16 + tt;
    u16* orow = obS + ((size_t)(z * 2 + b) * 1024 + t2) * 1024 + h * 64 + dd;
#pragma unroll
    for (int dt = 0; dt < 4; dt++) {
      *(floatx4*)(&Pf[l16 * 20 + quad * 4]) = oacc[nt][dt];   // [t][d] tile
      floatx4 val = *(const floatx4*)(&Pf[tt * 20 + dd]);     // wave in-order
      uint2 st; st.x = pack2bf(val[0], val[1]); st.y = pack2bf(val[2], val[3]);
      *(uint2*)(orow + dt * 16) = st;
    }
  }
}

// ---------------- fused: slot-sum (bf16 coalesced rows), /l, rmsnorm chain
__device__ __forceinline__ float block_sum(float v, float* red) {
  v += __shfl_xor(v, 32); v += __shfl_xor(v, 16); v += __shfl_xor(v, 8);
  v += __shfl_xor(v, 4);  v += __shfl_xor(v, 2);  v += __shfl_xor(v, 1);
  __syncthreads();
  if ((threadIdx.x & 63) == 0) red[threadIdx.x >> 6] = v;
  __syncthreads();
  return red[0] + red[1] + red[2] + red[3];
}

__global__ __launch_bounds__(256) void fused_norm(
    const u16* __restrict__ obS, const float* __restrict__ lbufp,
    const float* __restrict__ x, const float* __restrict__ lnw,
    const float* __restrict__ lwbuf, const float* __restrict__ flnw,
    const float* __restrict__ alphap, u16* __restrict__ y) {
  __shared__ float red[4];
  const int row = blockIdx.x, tid = threadIdx.x;  // row = b*1024+t
  float a[4] = {0.f, 0.f, 0.f, 0.f};
  const int nsl[3] = {1, 2, 3};
  const int sl[3][3] = {{5, 0, 0}, {0, 4, 0}, {1, 2, 3}};
#pragma unroll
  for (int l = 0; l < 3; l++) {
    float o0 = 0.f, o1 = 0.f, o2 = 0.f, o3 = 0.f, ls = 0.f;
#pragma unroll
    for (int si = 0; si < 3; si++) {
      if (si >= nsl[l]) break;
      int z = sl[l][si];
      uint2 v = ((const uint2*)(obS + ((size_t)z * 2048 + row) * 1024))[tid];
      o0 += bf2f((u16)(v.x & 0xffff)); o1 += bf2f((u16)(v.x >> 16));
      o2 += bf2f((u16)(v.y & 0xffff)); o3 += bf2f((u16)(v.y >> 16));
      ls += lbufp[((size_t)z * 2048 + row) * 16 + (tid >> 4)];
    }
    float linv = 1.f / ls;
    float v0 = o0 * linv, v1 = o1 * linv, v2 = o2 * linv, v3 = o3 * linv;
    float ss = v0 * v0 + v1 * v1 + v2 * v2 + v3 * v3;
    ss = block_sum(ss, red);
    float rstd = rsqrtf(ss * (1.f / 1024.f) + 1e-5f);
    float lw = lwbuf[l];
    float4 w = ((const float4*)(lnw + (size_t)l * 1024))[tid];
    a[0] += v0 * rstd * w.x * lw;
    a[1] += v1 * rstd * w.y * lw;
    a[2] += v2 * rstd * w.z * lw;
    a[3] += v3 * rstd * w.w * lw;
  }
  const float aa = alphap[0];
  float4 xv = ((const float4*)(x + (size_t)row * 1024))[tid];
  float v0 = a[0] + aa * xv.x, v1 = a[1] + aa * xv.y;
  float v2 = a[2] + aa * xv.z, v3 = a[3] + aa * xv.w;
  float ss = v0 * v0 + v1 * v1 + v2 * v2 + v3 * v3;
  ss = block_sum(ss, red);
  float rstd = rsqrtf(ss * (1.f / 1024.f) + 1e-5f);
  float4 fw = ((const float4*)flnw)[tid];
  ushort4 o;
  o.x = f2bf(v0 * rstd * fw.x); o.y = f2bf(v1 * rstd * fw.y);
  o.z = f2bf(v2 * rstd * fw.z); o.w = f2bf(v3 * rstd * fw.w);
  ((ushort4*)(y + (size_t)row * 1024))[tid] = o;
}

extern "C" void kernel_launch(void* const* d_in, const int* in_sizes, int n_in,
                              void* d_out, int out_size, void* d_ws, size_t ws_size,
                              hipStream_t stream) {
  const float* x     = (const float*)d_in[0];
  const float* cosb  = (const float*)d_in[1];
  const float* sinb  = (const float*)d_in[2];
  const float* qw    = (const float*)d_in[3];
  const float* kw    = (const float*)d_in[4];
  const float* vw    = (const float*)d_in[5];
  const float* lnw   = (const float*)d_in[6];
  const float* lam   = (const float*)d_in[7];
  const float* outw  = (const float*)d_in[8];
  const float* flnw  = (const float*)d_in[9];
  const float* alphap= (const float*)d_in[10];
  float* out = (float*)d_out;
  char* ws = (char*)d_ws;
  // workspace (~57.4 MB). Region [0,24M) is time-shared:
  //   phase 1 (prep/gemm_qkv): xb [0,4M) + wcat [4M,16M)
  //   phase 2 (attn/fused_norm): obS [0,24M)  bf16 [z][b][t][h*64+d]
  u16*   xb    = (u16*)  (ws + 0);          //  4 MB
  u16*   wcat  = (u16*)  (ws + 4194304);    // 12 MB
  u16*   obS   = (u16*)  (ws + 0);          // 24 MB (phase 2)
  u16*   outwb = (u16*)  (ws + 25165824);   //  2 MB
  float* lwbuf = (float*)(ws + 27262976);   //  1 KB
  u16*   qr    = (u16*)  (ws + 27264000);   // 12 MB  [3][2][16][1024][64]
  u16*   kr    = (u16*)  (ws + 39846912);   //  6 MB  [2][8][3072][64]
  u16*   vt    = (u16*)  (ws + 46138368);   //  6 MB  [2][8][64][3072]
  float* lbufp = (float*)(ws + 52429824);   // 768 KB [6][2048][16]
  u16*   yb    = (u16*)  (ws + 53216256);   //  4 MB

  prep_kernel<<<9216, 256, 0, stream>>>(x, qw, kw, vw, outw, lam, xb, wcat, outwb, lwbuf);
  gemm_qkv<<<768, 256, 0, stream>>>(xb, wcat, cosb, sinb, qr, kr, vt);
  attn_v7<<<768, 256, 0, stream>>>(qr, kr, vt, obS, lbufp);
  fused_norm<<<2048, 256, 0, stream>>>(obS, lbufp, x, lnw, lwbuf, flnw, alphap, yb);
  gemm_bt<<<dim3(32, 16), 256, 0, stream>>>(yb, outwb, out, 1024, 1024);
}